// Round 3
// baseline (6799.336 us; speedup 1.0000x reference)
//
#include <hip/hip_runtime.h>

// ODELayer: RK4 scan, T=256 steps, B=1024, NX=128, NU=32, NF=256, NIN=160.
// 64 persistent WGs x 256 threads; 16 batch rows per WG; whole scan in-kernel.
// dx-net weights resident in VGPRs as MFMA B-fragments; out-net weights
// streamed from L2 per step; activations via LDS ping-pong.
// DTYPE-ADAPTIVE (R2): block sniffs W2 to decide f32 vs bf16 buffers; all
// global loads/stores take the matching path. MFMA math is bf16 either way.

#define TSTEPS 256
#define BATCH  1024
#define NUQ    32
#define NXQ    128
#define NFQ    256
#define NINQ   160

typedef __attribute__((ext_vector_type(8))) short bf16x8;
typedef __attribute__((ext_vector_type(4))) float f32x4;
typedef unsigned short u16;

__device__ __forceinline__ float b2f(u16 s) {
  return __uint_as_float(((unsigned)s) << 16);
}
__device__ __forceinline__ u16 f2b(float f) {
  unsigned u = __float_as_uint(f);
  u = (u + 0x7FFFu + ((u >> 16) & 1u)) >> 16;
  return (u16)u;
}
__device__ __forceinline__ f32x4 mfma16(bf16x8 a, bf16x8 b, f32x4 c) {
  return __builtin_amdgcn_mfma_f32_16x16x32_bf16(a, b, c, 0, 0, 0);
}

// 8 consecutive weights at element index idx, as bf16 fragment, either dtype.
__device__ __forceinline__ bf16x8 ldw8(const void* W, int idx, bool f32f) {
  bf16x8 r;
  if (f32f) {
    const float* p = (const float*)W + idx;         // idx%8==0 -> 16B aligned
    f32x4 a = *reinterpret_cast<const f32x4*>(p);
    f32x4 b = *reinterpret_cast<const f32x4*>(p + 4);
    r[0] = (short)f2b(a[0]); r[1] = (short)f2b(a[1]);
    r[2] = (short)f2b(a[2]); r[3] = (short)f2b(a[3]);
    r[4] = (short)f2b(b[0]); r[5] = (short)f2b(b[1]);
    r[6] = (short)f2b(b[2]); r[7] = (short)f2b(b[3]);
  } else {
    r = *reinterpret_cast<const bf16x8*>((const u16*)W + idx);
  }
  return r;
}
__device__ __forceinline__ float ldsc(const void* B, int idx, bool f32f) {
  return f32f ? ((const float*)B)[idx] : b2f(((const u16*)B)[idx]);
}

__global__ __launch_bounds__(256, 1)
void ode_kernel(const void* __restrict__ uin,   // [256][1024][32]
                const void* __restrict__ x0,    // [1][1024][128]
                const void* __restrict__ dtraw, // scalar
                const void* __restrict__ Wlin,  // [128][160]
                const void* __restrict__ W1,    // [256][160]
                const void* __restrict__ b1,    // [256]
                const void* __restrict__ W2,    // [256][256]
                const void* __restrict__ b2,    // [256]
                const void* __restrict__ W3,    // [128][256]
                const void* __restrict__ b3,    // [128]
                const void* __restrict__ Wo1,   // [256][128]
                const void* __restrict__ bo1,   // [256]
                const void* __restrict__ Wo2,   // [256][256]
                const void* __restrict__ bo2,   // [256]
                const void* __restrict__ Wo3,   // [128][256]
                const void* __restrict__ bo3,   // [128]
                void* __restrict__ out)         // y[256][1024][128] ++ xf[1024][128]
{
  __shared__ u16 zb[16][168];
  __shared__ u16 h1[16][264];
  __shared__ u16 h2[16][264];
  __shared__ float linb[128][20];
  __shared__ float kcur[128][20];

  const int tid  = threadIdx.x;
  const int wg   = blockIdx.x;
  const int lane = tid & 63;
  const int w    = tid >> 6;
  const int ln   = lane & 15;
  const int q    = lane >> 4;
  const int row  = tid & 15;
  const int cg   = tid >> 4;

  // ---- dtype sniff: bf16-interp first 64 u16 of W2 (random, std 1e-4).
  // If data is f32, its mantissa-half u16s decode to huge bf16 values.
  bool f32f = false;
  {
    const u16* p = (const u16*)W2;
    for (int i = 0; i < 64; i++)
      if (fabsf(b2f(p[i])) > 1.0f) f32f = true;
  }

  float dt;
  {
    if (f32f) dt = *(const float*)dtraw;
    else {
      float dt_b = b2f(((const u16*)dtraw)[0]);
      float ab = fabsf(dt_b);
      dt = (ab >= 1e-6f && ab <= 1e3f) ? dt_b : *(const float*)dtraw;
    }
  }
  const float dt_half  = 0.5f * dt;
  const float dt_sixth = dt * (1.0f / 6.0f);
  const f32x4 zero4 = {0.0f, 0.0f, 0.0f, 0.0f};

  // ---- persistent dx-net B-fragments: B[k][n] = W[n][k] ----
  bf16x8 wcat[5][6];
#pragma unroll
  for (int kt = 0; kt < 5; kt++)
#pragma unroll
    for (int nt = 0; nt < 6; nt++) {
      int n = 96 * w + 16 * nt + ln;
      int k = 32 * kt + 8 * q;
      wcat[kt][nt] = (n < NFQ) ? ldw8(W1, n * NINQ + k, f32f)
                               : ldw8(Wlin, (n - NFQ) * NINQ + k, f32f);
    }
  bf16x8 w2f[8][4];
#pragma unroll
  for (int kt = 0; kt < 8; kt++)
#pragma unroll
    for (int nt = 0; nt < 4; nt++) {
      int n = 64 * w + 16 * nt + ln;
      w2f[kt][nt] = ldw8(W2, n * NFQ + 32 * kt + 8 * q, f32f);
    }
  bf16x8 w3f[8][2];
#pragma unroll
  for (int kt = 0; kt < 8; kt++)
#pragma unroll
    for (int nt = 0; nt < 2; nt++) {
      int n = 32 * w + 16 * nt + ln;
      w3f[kt][nt] = ldw8(W3, n * NFQ + 32 * kt + 8 * q, f32f);
    }

  float b1v[6], b2v[4], b3v[2], bo1v[4], bo2v[4], bo3v[2];
#pragma unroll
  for (int nt = 0; nt < 6; nt++) {
    int n = 96 * w + 16 * nt + ln;
    b1v[nt] = (n < NFQ) ? ldsc(b1, n, f32f) : 0.0f;
  }
#pragma unroll
  for (int nt = 0; nt < 4; nt++) {
    int n = 64 * w + 16 * nt + ln;
    b2v[nt]  = ldsc(b2, n, f32f);
    bo1v[nt] = ldsc(bo1, n, f32f);
    bo2v[nt] = ldsc(bo2, n, f32f);
  }
#pragma unroll
  for (int nt = 0; nt < 2; nt++) {
    int n = 32 * w + 16 * nt + ln;
    b3v[nt]  = ldsc(b3, n, f32f);
    bo3v[nt] = ldsc(bo3, n, f32f);
  }

  // ---- x state in registers; bf16(x) into zb cols 0..127 ----
  float xr[8];
  {
    int base = (wg * 16 + row) * NXQ + cg * 8;
    u16 tmp[8];
    if (f32f) {
      const float* xp = (const float*)x0 + base;
#pragma unroll
      for (int j = 0; j < 8; j++) { xr[j] = xp[j]; tmp[j] = f2b(xr[j]); }
    } else {
      const u16* xp = (const u16*)x0 + base;
#pragma unroll
      for (int j = 0; j < 8; j++) { tmp[j] = xp[j]; xr[j] = b2f(tmp[j]); }
    }
    *reinterpret_cast<bf16x8*>(&zb[row][cg * 8]) =
        *reinterpret_cast<const bf16x8*>(tmp);
  }

#pragma unroll 1
  for (int t = 0; t < TSTEPS; t++) {
    if (cg < 4) {
      long base = ((long)t * BATCH + wg * 16 + row) * NUQ + cg * 8;
      if (f32f) {
        const float* up = (const float*)uin + base;
        u16 tmp[8];
#pragma unroll
        for (int j = 0; j < 8; j++) tmp[j] = f2b(up[j]);
        *reinterpret_cast<bf16x8*>(&zb[row][128 + cg * 8]) =
            *reinterpret_cast<const bf16x8*>(tmp);
      } else {
        *reinterpret_cast<bf16x8*>(&zb[row][128 + cg * 8]) =
            *reinterpret_cast<const bf16x8*>((const u16*)uin + base);
      }
    }
    __syncthreads();

    float ks[8];
#pragma unroll
    for (int j = 0; j < 8; j++) ks[j] = 0.0f;

#pragma unroll 1
    for (int e = 0; e < 4; e++) {
      { // GEMM1: z[16x160] @ Wcat^T -> h1(relu) + lin(f32)
        bf16x8 a[5];
#pragma unroll
        for (int kt = 0; kt < 5; kt++)
          a[kt] = *reinterpret_cast<const bf16x8*>(&zb[ln][32 * kt + 8 * q]);
        f32x4 acc[6];
#pragma unroll
        for (int nt = 0; nt < 6; nt++) acc[nt] = zero4;
#pragma unroll
        for (int kt = 0; kt < 5; kt++)
#pragma unroll
          for (int nt = 0; nt < 6; nt++)
            acc[nt] = mfma16(a[kt], wcat[kt][nt], acc[nt]);
#pragma unroll
        for (int nt = 0; nt < 6; nt++) {
          int n = 96 * w + 16 * nt + ln;
          if (n < NFQ) {
#pragma unroll
            for (int r = 0; r < 4; r++)
              h1[4 * q + r][n] = f2b(fmaxf(acc[nt][r] + b1v[nt], 0.0f));
          } else {
            *reinterpret_cast<f32x4*>(&linb[n - NFQ][4 * q]) = acc[nt];
          }
        }
      }
      __syncthreads();
      { // GEMM2: h1 @ W2^T -> h2 (relu)
        bf16x8 a[8];
#pragma unroll
        for (int kt = 0; kt < 8; kt++)
          a[kt] = *reinterpret_cast<const bf16x8*>(&h1[ln][32 * kt + 8 * q]);
        f32x4 acc[4];
#pragma unroll
        for (int nt = 0; nt < 4; nt++) acc[nt] = zero4;
#pragma unroll
        for (int kt = 0; kt < 8; kt++)
#pragma unroll
          for (int nt = 0; nt < 4; nt++)
            acc[nt] = mfma16(a[kt], w2f[kt][nt], acc[nt]);
#pragma unroll
        for (int nt = 0; nt < 4; nt++) {
          int n = 64 * w + 16 * nt + ln;
#pragma unroll
          for (int r = 0; r < 4; r++)
            h2[4 * q + r][n] = f2b(fmaxf(acc[nt][r] + b2v[nt], 0.0f));
        }
      }
      __syncthreads();
      { // GEMM3: h2 @ W3^T + lin + b3 -> kcur (f32)
        bf16x8 a[8];
#pragma unroll
        for (int kt = 0; kt < 8; kt++)
          a[kt] = *reinterpret_cast<const bf16x8*>(&h2[ln][32 * kt + 8 * q]);
        f32x4 acc[2];
#pragma unroll
        for (int nt = 0; nt < 2; nt++) acc[nt] = zero4;
#pragma unroll
        for (int kt = 0; kt < 8; kt++)
#pragma unroll
          for (int nt = 0; nt < 2; nt++)
            acc[nt] = mfma16(a[kt], w3f[kt][nt], acc[nt]);
#pragma unroll
        for (int nt = 0; nt < 2; nt++) {
          int n = 32 * w + 16 * nt + ln;
          f32x4 lv = *reinterpret_cast<const f32x4*>(&linb[n][4 * q]);
          f32x4 o;
#pragma unroll
          for (int r = 0; r < 4; r++) o[r] = acc[nt][r] + lv[r] + b3v[nt];
          *reinterpret_cast<f32x4*>(&kcur[n][4 * q]) = o;
        }
      }
      __syncthreads();
      { // elementwise RK4 bookkeeping
        float wk = (e == 1 || e == 2) ? 2.0f : 1.0f;
        float cn = (e == 2) ? dt : dt_half;
        u16 zout[8];
#pragma unroll
        for (int j = 0; j < 8; j++) {
          float kv = kcur[cg * 8 + j][row];
          ks[j] += wk * kv;
          float xe;
          if (e == 3) { xr[j] += dt_sixth * ks[j]; xe = xr[j]; }
          else        { xe = xr[j] + cn * kv; }
          zout[j] = f2b(xe);
        }
        *reinterpret_cast<bf16x8*>(&zb[row][cg * 8]) =
            *reinterpret_cast<const bf16x8*>(zout);
      }
      __syncthreads();
    }

    // ---- out_net on x_new ----
    { // o1: zb[.,0:128] @ Wo1^T -> h1 (relu)
      f32x4 acc[4];
#pragma unroll
      for (int nt = 0; nt < 4; nt++) acc[nt] = zero4;
#pragma unroll 1
      for (int kh = 0; kh < 2; kh++) {
        bf16x8 av[2], bfr[2][4];
#pragma unroll
        for (int kk = 0; kk < 2; kk++) {
          int k = 32 * (2 * kh + kk) + 8 * q;
          av[kk] = *reinterpret_cast<const bf16x8*>(&zb[ln][k]);
#pragma unroll
          for (int nt = 0; nt < 4; nt++) {
            int n = 64 * w + 16 * nt + ln;
            bfr[kk][nt] = ldw8(Wo1, n * NXQ + k, f32f);
          }
        }
#pragma unroll
        for (int kk = 0; kk < 2; kk++)
#pragma unroll
          for (int nt = 0; nt < 4; nt++)
            acc[nt] = mfma16(av[kk], bfr[kk][nt], acc[nt]);
      }
#pragma unroll
      for (int nt = 0; nt < 4; nt++) {
        int n = 64 * w + 16 * nt + ln;
#pragma unroll
        for (int r = 0; r < 4; r++)
          h1[4 * q + r][n] = f2b(fmaxf(acc[nt][r] + bo1v[nt], 0.0f));
      }
    }
    __syncthreads();
    { // o2: h1 @ Wo2^T -> h2 (relu)
      f32x4 acc[4];
#pragma unroll
      for (int nt = 0; nt < 4; nt++) acc[nt] = zero4;
#pragma unroll 1
      for (int kh = 0; kh < 4; kh++) {
        bf16x8 av[2], bfr[2][4];
#pragma unroll
        for (int kk = 0; kk < 2; kk++) {
          int k = 32 * (2 * kh + kk) + 8 * q;
          av[kk] = *reinterpret_cast<const bf16x8*>(&h1[ln][k]);
#pragma unroll
          for (int nt = 0; nt < 4; nt++) {
            int n = 64 * w + 16 * nt + ln;
            bfr[kk][nt] = ldw8(Wo2, n * NFQ + k, f32f);
          }
        }
#pragma unroll
        for (int kk = 0; kk < 2; kk++)
#pragma unroll
          for (int nt = 0; nt < 4; nt++)
            acc[nt] = mfma16(av[kk], bfr[kk][nt], acc[nt]);
      }
#pragma unroll
      for (int nt = 0; nt < 4; nt++) {
        int n = 64 * w + 16 * nt + ln;
#pragma unroll
        for (int r = 0; r < 4; r++)
          h2[4 * q + r][n] = f2b(fmaxf(acc[nt][r] + bo2v[nt], 0.0f));
      }
    }
    __syncthreads();
    { // o3: h2 @ Wo3^T + bo3 -> y[t]
      f32x4 acc[2];
#pragma unroll
      for (int nt = 0; nt < 2; nt++) acc[nt] = zero4;
#pragma unroll 1
      for (int kh = 0; kh < 4; kh++) {
        bf16x8 av[2], bfr[2][2];
#pragma unroll
        for (int kk = 0; kk < 2; kk++) {
          int k = 32 * (2 * kh + kk) + 8 * q;
          av[kk] = *reinterpret_cast<const bf16x8*>(&h2[ln][k]);
#pragma unroll
          for (int nt = 0; nt < 2; nt++) {
            int n = 32 * w + 16 * nt + ln;
            bfr[kk][nt] = ldw8(Wo3, n * NFQ + k, f32f);
          }
        }
#pragma unroll
        for (int kk = 0; kk < 2; kk++)
#pragma unroll
          for (int nt = 0; nt < 2; nt++)
            acc[nt] = mfma16(av[kk], bfr[kk][nt], acc[nt]);
      }
      size_t ybase = ((size_t)t * BATCH + wg * 16) * NXQ;
#pragma unroll
      for (int nt = 0; nt < 2; nt++) {
        int n = 32 * w + 16 * nt + ln;
#pragma unroll
        for (int r = 0; r < 4; r++) {
          float v = acc[nt][r] + bo3v[nt];
          size_t idx = ybase + (size_t)(4 * q + r) * NXQ + n;
          if (f32f) ((float*)out)[idx] = v;
          else      ((u16*)out)[idx]   = f2b(v);
        }
      }
    }
    // next step's u-fill only touches zb cols 128..159 (not read by o1) — no
    // barrier needed here.
  }

  // x_final
  {
    size_t base = (size_t)TSTEPS * BATCH * NXQ + (size_t)(wg * 16 + row) * NXQ + cg * 8;
#pragma unroll
    for (int j = 0; j < 8; j++) {
      if (f32f) ((float*)out)[base + j] = xr[j];
      else      ((u16*)out)[base + j]   = f2b(xr[j]);
    }
  }
}

extern "C" void kernel_launch(void* const* d_in, const int* in_sizes, int n_in,
                              void* d_out, int out_size, void* d_ws, size_t ws_size,
                              hipStream_t stream) {
  ode_kernel<<<dim3(64), dim3(256), 0, stream>>>(
      d_in[0],  d_in[1],  d_in[2],  d_in[3],
      d_in[4],  d_in[5],  d_in[6],  d_in[7],
      d_in[8],  d_in[9],  d_in[10], d_in[11],
      d_in[12], d_in[13], d_in[14], d_in[15],
      d_out);
}

// Round 4
// 1735.469 us; speedup vs baseline: 3.9179x; 3.9179x over previous
//
#include <hip/hip_runtime.h>

// ODELayer RK4 scan. R4 structure:
//   Phase 1 (scan_kernel, 64 WG x 512 thr): 256-step RK4 chain, dx-net only.
//     Weights resident as MFMA B-fragments. RK4 state in C-layout registers
//     on the GEMM3 waves (no elementwise stage, no kcur/linb LDS buffers).
//     12 barriers/step. Writes x_new (bf16) per step to scratch + x_final.
//   Phase 2 (outnet_kernel, 512 WG x 512 thr): out_net over all 256*1024
//     rows as a register-weight GEMM, 2 barriers/slab, ping-pong LDS.
// All global data f32 (confirmed R3); MFMA math bf16, f32 accumulate.

#define TSTEPS 256
#define BATCH  1024
#define NUQ    32
#define NXQ    128
#define NFQ    256
#define NINQ   160
#define NY     ((size_t)TSTEPS * BATCH * NXQ)

typedef __attribute__((ext_vector_type(8))) short bf16x8;
typedef __attribute__((ext_vector_type(4))) short s16x4;
typedef __attribute__((ext_vector_type(4))) float f32x4;
typedef unsigned short u16;

__device__ __forceinline__ u16 f2b(float f) {
  unsigned u = __float_as_uint(f);
  u = (u + 0x7FFFu + ((u >> 16) & 1u)) >> 16;
  return (u16)u;
}
__device__ __forceinline__ f32x4 mfma16(bf16x8 a, bf16x8 b, f32x4 c) {
  return __builtin_amdgcn_mfma_f32_16x16x32_bf16(a, b, c, 0, 0, 0);
}
// 8 consecutive f32 weights -> bf16 fragment (16B-aligned source).
__device__ __forceinline__ bf16x8 ldw8f(const float* p) {
  f32x4 a = *reinterpret_cast<const f32x4*>(p);
  f32x4 b = *reinterpret_cast<const f32x4*>(p + 4);
  bf16x8 r;
  r[0] = (short)f2b(a[0]); r[1] = (short)f2b(a[1]);
  r[2] = (short)f2b(a[2]); r[3] = (short)f2b(a[3]);
  r[4] = (short)f2b(b[0]); r[5] = (short)f2b(b[1]);
  r[6] = (short)f2b(b[2]); r[7] = (short)f2b(b[3]);
  return r;
}

// ======================= Phase 1: the sequential scan =======================
__global__ __launch_bounds__(512, 2)
void scan_kernel(const float* __restrict__ uin,   // [256][1024][32]
                 const float* __restrict__ x0,    // [1024][128]
                 const float* __restrict__ dtp,
                 const float* __restrict__ Wlin,  // [128][160]
                 const float* __restrict__ W1,    // [256][160]
                 const float* __restrict__ b1,    // [256]
                 const float* __restrict__ W2,    // [256][256]
                 const float* __restrict__ b2,    // [256]
                 const float* __restrict__ W3,    // [128][256]
                 const float* __restrict__ b3,    // [128]
                 u16* __restrict__ xall,          // [256][1024][128] bf16
                 float* __restrict__ out)         // xf at out[NY..]
{
  __shared__ u16 zb[16][168];   // z = [x_eval | u], row-major, pad 168
  __shared__ u16 h1[16][264];
  __shared__ u16 h2[16][264];

  const int tid  = threadIdx.x;
  const int wg   = blockIdx.x;            // batch rows wg*16..+15
  const int lane = tid & 63;
  const int v    = tid >> 6;              // wave 0..7
  const int ln   = lane & 15;
  const int q    = lane >> 4;

  const float dt  = dtp[0];
  const float dth = 0.5f * dt;
  const float dt6 = dt * (1.0f / 6.0f);
  const f32x4 zero4 = {0.f, 0.f, 0.f, 0.f};

  // column ownership: wave v owns cols n1=16v+ln (and n2=n1+128 where N=256)
  const int n1 = 16 * v + ln;
  const int n2 = 128 + n1;

  // ---- resident B-fragments (B[k][n] = W[n][k]) ----
  bf16x8 wc[5][3];                        // GEMM1: h1-tile n1, h1-tile n2, lin-tile n1
#pragma unroll
  for (int kt = 0; kt < 5; kt++) {
    int k = 32 * kt + 8 * q;
    wc[kt][0] = ldw8f(W1 + n1 * NINQ + k);
    wc[kt][1] = ldw8f(W1 + n2 * NINQ + k);
    wc[kt][2] = ldw8f(Wlin + n1 * NINQ + k);
  }
  bf16x8 w2f[8][2];                       // GEMM2: tiles n1, n2
#pragma unroll
  for (int kt = 0; kt < 8; kt++) {
    int k = 32 * kt + 8 * q;
    w2f[kt][0] = ldw8f(W2 + n1 * NFQ + k);
    w2f[kt][1] = ldw8f(W2 + n2 * NFQ + k);
  }
  bf16x8 w3f[8];                          // GEMM3: tile n1
#pragma unroll
  for (int kt = 0; kt < 8; kt++)
    w3f[kt] = ldw8f(W3 + n1 * NFQ + 32 * kt + 8 * q);

  const float b1a = b1[n1], b1b = b1[n2];
  const float b2a = b2[n1], b2b = b2[n2];
  const float b3a = b3[n1];

  // RK4 state in C-layout: this lane holds x[rows 4q+r][col n1], r=0..3
  float xs[4], ksum[4];
#pragma unroll
  for (int r = 0; r < 4; r++)
    xs[r] = x0[(wg * 16 + 4 * q + r) * NXQ + n1];

  // zb init: bf16(x0) cols 0..127 (each thread 4 cols) + u[0] cols 128..159
  {
    int r = tid & 15, cG = tid >> 4;      // cG 0..31
    const float* xp = &x0[(wg * 16 + r) * NXQ + 4 * cG];
    s16x4 t4;
#pragma unroll
    for (int j = 0; j < 4; j++) t4[j] = (short)f2b(xp[j]);
    *reinterpret_cast<s16x4*>(&zb[r][4 * cG]) = t4;
    zb[ln][128 + 4 * v + q] =
        f2b(uin[(size_t)(wg * 16 + ln) * NUQ + 4 * v + q]);
  }
  __syncthreads();

#pragma unroll 1
  for (int t = 0; t < TSTEPS; t++) {
#pragma unroll 1
    for (int e = 0; e < 4; e++) {
      // ---- S1: z @ Wcat^T -> h1 (relu) + lin (regs) ----
      f32x4 acc0 = zero4, acc1 = zero4, accl = zero4;
      {
        bf16x8 a[5];
#pragma unroll
        for (int kt = 0; kt < 5; kt++)
          a[kt] = *reinterpret_cast<const bf16x8*>(&zb[ln][32 * kt + 8 * q]);
#pragma unroll
        for (int kt = 0; kt < 5; kt++) {
          acc0 = mfma16(a[kt], wc[kt][0], acc0);
          acc1 = mfma16(a[kt], wc[kt][1], acc1);
          accl = mfma16(a[kt], wc[kt][2], accl);
        }
#pragma unroll
        for (int r = 0; r < 4; r++) {
          h1[4 * q + r][n1] = f2b(fmaxf(acc0[r] + b1a, 0.f));
          h1[4 * q + r][n2] = f2b(fmaxf(acc1[r] + b1b, 0.f));
        }
      }
      __syncthreads();
      // ---- S2: h1 @ W2^T -> h2 (relu) ----
      {
        bf16x8 c[8];
#pragma unroll
        for (int kt = 0; kt < 8; kt++)
          c[kt] = *reinterpret_cast<const bf16x8*>(&h1[ln][32 * kt + 8 * q]);
        f32x4 d0 = zero4, d1 = zero4;
#pragma unroll
        for (int kt = 0; kt < 8; kt++) {
          d0 = mfma16(c[kt], w2f[kt][0], d0);
          d1 = mfma16(c[kt], w2f[kt][1], d1);
        }
#pragma unroll
        for (int r = 0; r < 4; r++) {
          h2[4 * q + r][n1] = f2b(fmaxf(d0[r] + b2a, 0.f));
          h2[4 * q + r][n2] = f2b(fmaxf(d1[r] + b2b, 0.f));
        }
      }
      __syncthreads();
      // ---- S3: h2 @ W3^T + lin + b3 -> k ; RK4 update in-register ----
      {
        bf16x8 g[8];
#pragma unroll
        for (int kt = 0; kt < 8; kt++)
          g[kt] = *reinterpret_cast<const bf16x8*>(&h2[ln][32 * kt + 8 * q]);
        f32x4 kk = zero4;
#pragma unroll
        for (int kt = 0; kt < 8; kt++) kk = mfma16(g[kt], w3f[kt], kk);

        const float wk = (e == 1 || e == 2) ? 2.0f : 1.0f;
        const float cn = (e == 2) ? dt : dth;
        u16 zo[4];
#pragma unroll
        for (int r = 0; r < 4; r++) {
          float kv = kk[r] + accl[r] + b3a;
          if (e == 0) ksum[r] = kv; else ksum[r] += wk * kv;
          float xe;
          if (e == 3) { xs[r] += dt6 * ksum[r]; xe = xs[r]; }
          else        { xe = xs[r] + cn * kv; }
          zo[r] = f2b(xe);
          zb[4 * q + r][n1] = zo[r];
        }
        if (e == 3) {
          // x_new (bf16) -> scratch for phase 2
#pragma unroll
          for (int r = 0; r < 4; r++)
            xall[((size_t)t * BATCH + wg * 16 + 4 * q + r) * NXQ + n1] = zo[r];
          // prefetch u[t+1] into zb cols 128..159 (last reader was eval3 S1)
          if (t + 1 < TSTEPS)
            zb[ln][128 + 4 * v + q] = f2b(
                uin[((size_t)(t + 1) * BATCH + wg * 16 + ln) * NUQ + 4 * v + q]);
        }
      }
      __syncthreads();
    }
  }

  // x_final (f32)
#pragma unroll
  for (int r = 0; r < 4; r++)
    out[NY + (size_t)(wg * 16 + 4 * q + r) * NXQ + n1] = xs[r];
}

// ======================= Phase 2: bulk out_net GEMM =========================
// Processes y rows [16*slab .. ) for slabs in [slab0+blk*spw, slab_end).
__global__ __launch_bounds__(512, 2)
void outnet_kernel(const u16* __restrict__ xall,  // [rows][128] bf16
                   const float* __restrict__ Wo1, const float* __restrict__ bo1,
                   const float* __restrict__ Wo2, const float* __restrict__ bo2,
                   const float* __restrict__ Wo3, const float* __restrict__ bo3,
                   float* __restrict__ out,       // y [rows][128] f32
                   int slab0, int slab_end, int spw)
{
  __shared__ u16 h1[2][16][264];
  __shared__ u16 h2[2][16][264];

  const int tid  = threadIdx.x;
  const int lane = tid & 63;
  const int v    = tid >> 6;
  const int ln   = lane & 15;
  const int q    = lane >> 4;
  const int n1   = 16 * v + ln;
  const int n2   = 128 + n1;
  const f32x4 zero4 = {0.f, 0.f, 0.f, 0.f};

  bf16x8 f1[4][2];
#pragma unroll
  for (int kt = 0; kt < 4; kt++) {
    int k = 32 * kt + 8 * q;
    f1[kt][0] = ldw8f(Wo1 + n1 * NXQ + k);
    f1[kt][1] = ldw8f(Wo1 + n2 * NXQ + k);
  }
  bf16x8 f2[8][2];
#pragma unroll
  for (int kt = 0; kt < 8; kt++) {
    int k = 32 * kt + 8 * q;
    f2[kt][0] = ldw8f(Wo2 + n1 * NFQ + k);
    f2[kt][1] = ldw8f(Wo2 + n2 * NFQ + k);
  }
  bf16x8 f3[8];
#pragma unroll
  for (int kt = 0; kt < 8; kt++)
    f3[kt] = ldw8f(Wo3 + n1 * NFQ + 32 * kt + 8 * q);

  const float c1a = bo1[n1], c1b = bo1[n2];
  const float c2a = bo2[n1], c2b = bo2[n2];
  const float c3  = bo3[n1];

  const int s0  = slab0 + (int)blockIdx.x * spw;
  int cnt = slab_end - s0; if (cnt > spw) cnt = spw;
  if (cnt <= 0) return;

  bf16x8 a[4], an[4];
#pragma unroll
  for (int kt = 0; kt < 4; kt++)
    a[kt] = *reinterpret_cast<const bf16x8*>(
        &xall[((size_t)16 * s0 + ln) * NXQ + 32 * kt + 8 * q]);

#pragma unroll 1
  for (int i = 0; i < cnt; i++) {
    const int s = s0 + i, par = i & 1;
    if (i + 1 < cnt) {
#pragma unroll
      for (int kt = 0; kt < 4; kt++)
        an[kt] = *reinterpret_cast<const bf16x8*>(
            &xall[((size_t)16 * (s + 1) + ln) * NXQ + 32 * kt + 8 * q]);
    }
    // o1
    {
      f32x4 d0 = zero4, d1 = zero4;
#pragma unroll
      for (int kt = 0; kt < 4; kt++) {
        d0 = mfma16(a[kt], f1[kt][0], d0);
        d1 = mfma16(a[kt], f1[kt][1], d1);
      }
#pragma unroll
      for (int r = 0; r < 4; r++) {
        h1[par][4 * q + r][n1] = f2b(fmaxf(d0[r] + c1a, 0.f));
        h1[par][4 * q + r][n2] = f2b(fmaxf(d1[r] + c1b, 0.f));
      }
    }
    __syncthreads();
    // o2
    {
      bf16x8 c[8];
#pragma unroll
      for (int kt = 0; kt < 8; kt++)
        c[kt] = *reinterpret_cast<const bf16x8*>(&h1[par][ln][32 * kt + 8 * q]);
      f32x4 e0 = zero4, e1 = zero4;
#pragma unroll
      for (int kt = 0; kt < 8; kt++) {
        e0 = mfma16(c[kt], f2[kt][0], e0);
        e1 = mfma16(c[kt], f2[kt][1], e1);
      }
#pragma unroll
      for (int r = 0; r < 4; r++) {
        h2[par][4 * q + r][n1] = f2b(fmaxf(e0[r] + c2a, 0.f));
        h2[par][4 * q + r][n2] = f2b(fmaxf(e1[r] + c2b, 0.f));
      }
    }
    __syncthreads();
    // o3 -> y (f32); no trailing barrier (ping-pong buffers)
    {
      bf16x8 g[8];
#pragma unroll
      for (int kt = 0; kt < 8; kt++)
        g[kt] = *reinterpret_cast<const bf16x8*>(&h2[par][ln][32 * kt + 8 * q]);
      f32x4 y = zero4;
#pragma unroll
      for (int kt = 0; kt < 8; kt++) y = mfma16(g[kt], f3[kt], y);
#pragma unroll
      for (int r = 0; r < 4; r++)
        out[((size_t)16 * s + 4 * q + r) * NXQ + n1] = y[r] + c3;
    }
#pragma unroll
    for (int kt = 0; kt < 4; kt++) a[kt] = an[kt];
  }
}

extern "C" void kernel_launch(void* const* d_in, const int* in_sizes, int n_in,
                              void* d_out, int out_size, void* d_ws, size_t ws_size,
                              hipStream_t stream) {
  const float* uin  = (const float*)d_in[0];
  const float* x0   = (const float*)d_in[1];
  const float* dtp  = (const float*)d_in[2];
  const float* Wlin = (const float*)d_in[3];
  const float* W1   = (const float*)d_in[4];
  const float* b1   = (const float*)d_in[5];
  const float* W2   = (const float*)d_in[6];
  const float* b2   = (const float*)d_in[7];
  const float* W3   = (const float*)d_in[8];
  const float* b3   = (const float*)d_in[9];
  const float* Wo1  = (const float*)d_in[10];
  const float* bo1  = (const float*)d_in[11];
  const float* Wo2  = (const float*)d_in[12];
  const float* bo2  = (const float*)d_in[13];
  const float* Wo3  = (const float*)d_in[14];
  const float* bo3  = (const float*)d_in[15];
  float* out = (float*)d_out;

  const size_t xall_bytes = NY * sizeof(u16);   // 64 MiB
  const bool ws_ok = (ws_size >= xall_bytes);
  u16* xall = ws_ok ? (u16*)d_ws : (u16*)d_out;  // fallback: front of y region

  scan_kernel<<<dim3(64), dim3(512), 0, stream>>>(
      uin, x0, dtp, Wlin, W1, b1, W2, b2, W3, b3, xall, out);

  const int nslab = TSTEPS * BATCH / 16;        // 16384
  if (ws_ok) {
    const int spw = 32;
    outnet_kernel<<<dim3(nslab / spw), dim3(512), 0, stream>>>(
        xall, Wo1, bo1, Wo2, bo2, Wo3, bo3, out, 0, nslab, spw);
  } else {
    // y[slab s] overwrites x-slabs [2s,2s+2): process [S,2S) in halving
    // passes so clobbered x-slabs are always already consumed.
    for (int S = nslab / 2; S >= 1; S >>= 1) {
      int grid = S < 512 ? S : 512;
      int spw  = (S + grid - 1) / grid;
      outnet_kernel<<<dim3(grid), dim3(512), 0, stream>>>(
          xall, Wo1, bo1, Wo2, bo2, Wo3, bo3, out, S, 2 * S, spw);
    }
    outnet_kernel<<<dim3(1), dim3(512), 0, stream>>>(
        xall, Wo1, bo1, Wo2, bo2, Wo3, bo3, out, 0, 1, 1);
  }
}